// Round 12
// baseline (209.392 us; speedup 1.0000x reference)
//
#include <hip/hip_runtime.h>
#include <hip/hip_bf16.h>
#include <math.h>
#include <stdint.h>

#define B_ 4
#define T_ 1024
#define S_ 1024
#define D_ 1024
#define H_ 16
#define DH_ 64

static constexpr float EPSV = 1e-5f;
static constexpr float LOG2E = 1.4426950408889634f;
static constexpr float NEG2 = -1.4426950e9f;        // -1e9 * log2e
static constexpr float SCALE_Q = 0.125f * LOG2E;    // DH^-0.5 * log2e

typedef __attribute__((ext_vector_type(8))) short short8;
typedef __attribute__((ext_vector_type(4))) float f32x4;

#define MFMA_BF16 __builtin_amdgcn_mfma_f32_16x16x32_bf16

__device__ __forceinline__ ushort f2bf(float f) {
  union { float f; unsigned u; } v; v.f = f;
  unsigned r = (v.u + 0x7FFFu + ((v.u >> 16) & 1u)) >> 16;
  return (ushort)r;
}
__device__ __forceinline__ float bf2f(ushort u) {
  union { unsigned u; float f; } v; v.u = (unsigned)u << 16;
  return v.f;
}
// raw v_exp_f32: computes 2^x in one VALU op
__device__ __forceinline__ float exp2_fast(float x) {
  float r;
  asm("v_exp_f32 %0, %1" : "=v"(r) : "v"(x));
  return r;
}
// pack two f32 -> two bf16 (RNE) in one op
__device__ __forceinline__ unsigned cvt_pk_bf16(float lo, float hi) {
  unsigned r;
  asm("v_cvt_pk_bf16_f32 %0, %1, %2" : "=v"(r) : "v"(lo), "v"(hi));
  return r;
}

// async global->LDS, 16B per lane, wave-uniform LDS base + lane*16
__device__ __forceinline__ void gl_lds16(const ushort* g, ushort* l) {
  __builtin_amdgcn_global_load_lds(
      (const __attribute__((address_space(1))) unsigned int*)g,
      (__attribute__((address_space(3))) unsigned int*)l, 16, 0, 0);
}

// ---------------------------------------------------------------------------
// Fused prep: q/k/v converts [0,12288), weight converts [12288,16384),
// biasm = (mask ? -1e9 : bias) * log2e as bf16 [16384,24576).
// ---------------------------------------------------------------------------
__global__ __launch_bounds__(256) void k_prep(
    const float* __restrict__ q, const float* __restrict__ k,
    const float* __restrict__ v, const float* __restrict__ Wq,
    const float* __restrict__ Wk, const float* __restrict__ Wv,
    const float* __restrict__ Wo, const float* __restrict__ bias,
    const int* __restrict__ mask, ushort* __restrict__ qb,
    ushort* __restrict__ kb, ushort* __restrict__ vb,
    ushort* __restrict__ Wqb, ushort* __restrict__ Wkb,
    ushort* __restrict__ Wvb, ushort* __restrict__ Wob,
    ushort* __restrict__ bm) {
  const int bid = blockIdx.x;
  if (bid < 12288) {
    const int which = bid >> 12, local = bid & 4095;
    const float* src = (which == 0) ? q : (which == 1) ? k : v;
    ushort* dst = (which == 0) ? qb : (which == 1) ? kb : vb;
    const int i = (local * 256 + threadIdx.x) * 4;
    float4 t = *(const float4*)(src + i);
    *(ushort4*)(dst + i) = make_ushort4(f2bf(t.x), f2bf(t.y), f2bf(t.z), f2bf(t.w));
  } else if (bid < 16384) {
    const int wv_ = bid - 12288;
    const int which = wv_ >> 10, local = wv_ & 1023;
    const float* src = (which == 0) ? Wq : (which == 1) ? Wk : (which == 2) ? Wv : Wo;
    ushort* dst = (which == 0) ? Wqb : (which == 1) ? Wkb : (which == 2) ? Wvb : Wob;
    const int i = (local * 256 + threadIdx.x) * 4;
    float4 t = *(const float4*)(src + i);
    *(ushort4*)(dst + i) = make_ushort4(f2bf(t.x), f2bf(t.y), f2bf(t.z), f2bf(t.w));
  } else {
    const size_t i = ((size_t)(bid - 16384) * 256 + threadIdx.x) * 8;
    const size_t mi = i & (size_t)(T_ * S_ - 1);
    float4 b0 = *(const float4*)(bias + i);
    float4 b1 = *(const float4*)(bias + i + 4);
    int4 m0 = *(const int4*)(mask + mi);
    int4 m1 = *(const int4*)(mask + mi + 4);
    ushort o[8];
    o[0] = f2bf(m0.x ? NEG2 : b0.x * LOG2E); o[1] = f2bf(m0.y ? NEG2 : b0.y * LOG2E);
    o[2] = f2bf(m0.z ? NEG2 : b0.z * LOG2E); o[3] = f2bf(m0.w ? NEG2 : b0.w * LOG2E);
    o[4] = f2bf(m1.x ? NEG2 : b1.x * LOG2E); o[5] = f2bf(m1.y ? NEG2 : b1.y * LOG2E);
    o[6] = f2bf(m1.z ? NEG2 : b1.z * LOG2E); o[7] = f2bf(m1.w ? NEG2 : b1.w * LOG2E);
    *(uint4*)(bm + i) = *(uint4*)o;
  }
}

// ---------------------------------------------------------------------------
// bf16 MFMA GEMM: Y = A[4096,1024] @ W[1024,1024]^T.
// Staging via global_load_lds (width 16), linear [128][32] LDS tiles.
// MODE 0: f32 flat; MODE 1: bf16 head-split; MODE 2: bf16 head-split transposed.
// ---------------------------------------------------------------------------
template <int MODE>
__global__ __launch_bounds__(256) void k_gemm(const ushort* __restrict__ A,
                                              const ushort* __restrict__ W,
                                              void* __restrict__ Yv,
                                              float scale) {
  __shared__ ushort At[128][32];   // linear: required by global_load_lds
  __shared__ ushort Wt[128][32];
  const int tid = threadIdx.x;
  const int l = tid & 63, w = tid >> 6;
  const int wm = (w >> 1) * 64, wn = (w & 1) * 64;
  const int r16 = l & 15, g = l >> 4;
  const int i0 = blockIdx.x * 128, j0 = blockIdx.y * 128;
  const int srow = (l >> 2), scol = (l & 3) << 3;
  f32x4 acc[4][4] = {};

  for (int k0 = 0; k0 < D_; k0 += 32) {
    __syncthreads();
#pragma unroll
    for (int u = 0; u < 2; ++u) {
      const int row = w * 32 + u * 16 + srow;
      gl_lds16(&A[(size_t)(i0 + row) * D_ + k0 + scol], &At[w * 32 + u * 16][0]);
      gl_lds16(&W[(size_t)(j0 + row) * D_ + k0 + scol], &Wt[w * 32 + u * 16][0]);
    }
    __syncthreads();
    short8 a0[4], b0[4];
#pragma unroll
    for (int i = 0; i < 4; ++i) a0[i] = *(const short8*)&At[wm + 16 * i + r16][g * 8];
#pragma unroll
    for (int j = 0; j < 4; ++j) b0[j] = *(const short8*)&Wt[wn + 16 * j + r16][g * 8];
#pragma unroll
    for (int i = 0; i < 4; ++i)
#pragma unroll
      for (int j = 0; j < 4; ++j)
        acc[i][j] = MFMA_BF16(a0[i], b0[j], acc[i][j], 0, 0, 0);
  }

#pragma unroll
  for (int i = 0; i < 4; ++i)
#pragma unroll
    for (int j = 0; j < 4; ++j) {
      if (MODE == 2) {
        const int row0 = i0 + wm + 16 * i + 4 * g;
        const int col = j0 + wn + 16 * j + r16;
        const int bb = row0 >> 10, s = row0 & 1023;
        const int hh = col >> 6, dh = col & 63;
        ushort4 pw;
        pw.x = f2bf(acc[i][j][0] * scale); pw.y = f2bf(acc[i][j][1] * scale);
        pw.z = f2bf(acc[i][j][2] * scale); pw.w = f2bf(acc[i][j][3] * scale);
        *(ushort4*)&((ushort*)Yv)[((size_t)(bb * H_ + hh) * DH_ + dh) * 1024 + s] = pw;
      } else {
#pragma unroll
        for (int r = 0; r < 4; ++r) {
          const int row = i0 + wm + 16 * i + 4 * g + r;
          const int col = j0 + wn + 16 * j + r16;
          const float vv = acc[i][j][r] * scale;
          if (MODE == 0) {
            ((float*)Yv)[(size_t)row * D_ + col] = vv;
          } else {
            const int b = row >> 10, t = row & 1023;
            const int h = col >> 6, dh = col & 63;
            ((ushort*)Yv)[(((size_t)(b * H_ + h) * 1024) + t) * DH_ + dh] = f2bf(vv);
          }
        }
      }
    }
}

// ---------------------------------------------------------------------------
// Column sum-of-exp2 via MFMA (R7 version, unchanged).
// ---------------------------------------------------------------------------
__global__ __launch_bounds__(256, 4) void k_colstats(const ushort* __restrict__ Qh,
                                                     const ushort* __restrict__ Kh,
                                                     const ushort* __restrict__ biasm,
                                                     float* __restrict__ pc) {
  __shared__ ushort Qt[128][72];
  __shared__ ushort U[9216];
  ushort (*Kt)[72] = (ushort(*)[72])U;
  typedef ushort Row144[144];
  Row144* Bm0 = (Row144*)U;
  Row144* Bm1 = (Row144*)(U + 4608);

  const int z = blockIdx.z, b = z & 3, h = z >> 2;
  const int s0 = blockIdx.x * 128, t0 = blockIdx.y * 128;
  const int tid = threadIdx.x, l = tid & 63, w = tid >> 6;
  const int r16 = l & 15, g = l >> 4;

  const ushort* qsrc = Qh + ((size_t)((b * H_ + h) * 1024) + t0) * DH_;
  const ushort* ksrc = Kh + ((size_t)((b * H_ + h) * 1024) + s0) * DH_;
#pragma unroll
  for (int u = 0; u < 4; ++u) {
    const int lin = u * 256 + tid;
    const int row = lin >> 3, c8 = (lin & 7) << 3;
    *(uint4*)&Qt[row][c8] = *(const uint4*)&qsrc[(size_t)row * DH_ + c8];
    *(uint4*)&Kt[row][c8] = *(const uint4*)&ksrc[(size_t)row * DH_ + c8];
  }
  __syncthreads();

  f32x4 acc[8][2] = {};
#pragma unroll
  for (int kc = 0; kc < 2; ++kc) {
    short8 bk0 = *(const short8*)&Kt[w * 32 + r16][kc * 32 + g * 8];
    short8 bk1 = *(const short8*)&Kt[w * 32 + 16 + r16][kc * 32 + g * 8];
#pragma unroll
    for (int i = 0; i < 8; ++i) {
      short8 a = *(const short8*)&Qt[16 * i + r16][kc * 32 + g * 8];
      acc[i][0] = MFMA_BF16(a, bk0, acc[i][0], 0, 0, 0);
      acc[i][1] = MFMA_BF16(a, bk1, acc[i][1], 0, 0, 0);
    }
  }
  __syncthreads();

  const ushort* bsrc = biasm + ((size_t)h * 1024 + t0) * 1024 + s0;
#pragma unroll
  for (int u = 0; u < 2; ++u) {
    const int lin = u * 256 + tid;
    const int row = lin >> 4, c8 = (lin & 15) << 3;
    *(uint4*)&Bm0[row][c8] = *(const uint4*)&bsrc[(size_t)row * 1024 + c8];
  }
  __syncthreads();

  float cs0 = 0.f, cs1 = 0.f;
  const int col0 = w * 32 + r16;
#pragma unroll
  for (int c = 0; c < 4; ++c) {
    Row144* cur = (c & 1) ? Bm1 : Bm0;
    if (c < 3) {
      Row144* nxt = (c & 1) ? Bm0 : Bm1;
#pragma unroll
      for (int u = 0; u < 2; ++u) {
        const int lin = u * 256 + tid;
        const int row = lin >> 4, c8 = (lin & 15) << 3;
        *(uint4*)&nxt[row][c8] =
            *(const uint4*)&bsrc[(size_t)((c + 1) * 32 + row) * 1024 + c8];
      }
    }
#pragma unroll
    for (int ii = 0; ii < 2; ++ii) {
      const int i = 2 * c + ii;
      const int lrow = 16 * ii + 4 * g;
#pragma unroll
      for (int r = 0; r < 4; ++r) {
        cs0 += exp2_fast(acc[i][0][r] + bf2f(cur[lrow + r][col0]));
        cs1 += exp2_fast(acc[i][1][r] + bf2f(cur[lrow + r][col0 + 16]));
      }
    }
    __syncthreads();
  }

  cs0 += __shfl_xor(cs0, 16); cs0 += __shfl_xor(cs0, 32);
  cs1 += __shfl_xor(cs1, 16); cs1 += __shfl_xor(cs1, 32);
  if (g == 0) {
    const size_t base = ((size_t)b * 1024 + s0 + col0) * 128 + h * 8 + blockIdx.y;
    pc[base] = cs0;
    pc[base + 16 * 128] = cs1;
  }
}

// ---------------------------------------------------------------------------
// Combine 128 partial sums per (b,s) -> Civ = 1/C (R7 version).
// ---------------------------------------------------------------------------
__global__ __launch_bounds__(128) void k_combine(const float* __restrict__ pc,
                                                 float* __restrict__ Civ) {
  const int bs = blockIdx.x, tid = threadIdx.x;
  float c = pc[(size_t)bs * 128 + tid];
  __shared__ float sc[128];
  sc[tid] = c;
  __syncthreads();
  for (int off = 64; off > 0; off >>= 1) {
    if (tid < off) sc[tid] += sc[tid + off];
    __syncthreads();
  }
  if (tid == 0) {
    const float C = sc[0];
    Civ[bs] = (C > 0.f) ? 1.f / C : 0.f;
  }
}

// ---------------------------------------------------------------------------
// Attention pass (R12): R11's XCD-local decode + K fragments direct from
// global (L2-local now). No Kt buffer: LDS 35.3 KB -> 4 blocks/CU, grid
// exactly resident. K loads issue before the barrier; latency hides under
// V/bias staging.
// ---------------------------------------------------------------------------
__global__ __launch_bounds__(256, 4) void k_attn(const ushort* __restrict__ Qh,
                                                 const ushort* __restrict__ Kh,
                                                 const ushort* __restrict__ VhT,
                                                 const ushort* __restrict__ biasm,
                                                 const float* __restrict__ Civ,
                                                 ushort* __restrict__ O) {
  __shared__ ushort VtT[64][132];    // 16896 B  (d rows, s cols)
  __shared__ ushort BmPt[64][132];   // 16896 B  (t rows, s cols; bias then P)
  __shared__ float Cih[128];
  __shared__ float Rp[4][64];

  const int bid = blockIdx.x;
  const int tt = bid >> 6;           // t-tile (16)
  const int bh = bid & 63;           // XCD = bh % 8 for all tt
  const int b = bh >> 4, h = bh & 15;
  const int t0 = tt * 64;

  const int tid = threadIdx.x, l = tid & 63, w = tid >> 6;
  const int r16 = l & 15, g = l >> 4;
  const size_t kvbase = (size_t)bh * 1024 * DH_;
  const size_t vbase  = (size_t)bh * DH_ * 1024;

  short8 aq[4][2];
#pragma unroll
  for (int i = 0; i < 4; ++i) {
    const ushort* qr = Qh + ((size_t)bh * 1024 + t0 + 16 * i + r16) * DH_;
    aq[i][0] = *(const short8*)(qr + g * 8);
    aq[i][1] = *(const short8*)(qr + 32 + g * 8);
  }

  f32x4 aco[4] = {};
  float rloc[4] = {};

#pragma unroll 1
  for (int sc = 0; sc < 8; ++sc) {
    const int s0c = sc * 128;

    // issue K fragment loads first (L2-local): hide under staging + barrier
    const ushort* kr0 = Kh + kvbase + (size_t)(s0c + 16 * (2 * w) + r16) * DH_;
    const ushort* kr1 = Kh + kvbase + (size_t)(s0c + 16 * (2 * w + 1) + r16) * DH_;
    short8 k00 = *(const short8*)(kr0 + g * 8);
    short8 k01 = *(const short8*)(kr0 + 32 + g * 8);
    short8 k10 = *(const short8*)(kr1 + g * 8);
    short8 k11 = *(const short8*)(kr1 + 32 + g * 8);

    __syncthreads();   // previous chunk's VtT/BmPt consumed

    {
      const ushort* vsrc = VhT + vbase + s0c;
      const ushort* bsrc = biasm + ((size_t)h * 1024 + t0) * 1024 + s0c;
#pragma unroll
      for (int u = 0; u < 4; ++u) {
        const int lin = u * 256 + tid;
        const int row = lin >> 4, c8 = (lin & 15) << 3;
        *(uint4*)&VtT[row][c8] = *(const uint4*)&vsrc[(size_t)row * 1024 + c8];
        *(uint4*)&BmPt[row][c8] = *(const uint4*)&bsrc[(size_t)row * 1024 + c8];
      }
      if (tid < 128) Cih[tid] = Civ[(size_t)b * 1024 + s0c + tid];
    }
    __syncthreads();

    // ---- QK (A = K regs, B = Q regs) + exp, per jf ----
#pragma unroll
    for (int j2 = 0; j2 < 2; ++j2) {
      const int jf = 2 * w + j2;
      f32x4 as[4] = {};
      const short8 kf0 = j2 ? k10 : k00;
      const short8 kf1 = j2 ? k11 : k01;
#pragma unroll
      for (int i = 0; i < 4; ++i) {
        as[i] = MFMA_BF16(kf0, aq[i][0], as[i], 0, 0, 0);
        as[i] = MFMA_BF16(kf1, aq[i][1], as[i], 0, 0, 0);
      }
      const int scol = 16 * jf + 4 * g;
      const float4 cv = *(const float4*)&Cih[scol];
#pragma unroll
      for (int i = 0; i < 4; ++i) {
        const int srow = 16 * i + r16;
        ushort4 bv4 = *(const ushort4*)&BmPt[srow][scol];
        const float p0 = exp2_fast(as[i][0] + bf2f(bv4.x)) * cv.x;
        const float p1 = exp2_fast(as[i][1] + bf2f(bv4.y)) * cv.y;
        const float p2 = exp2_fast(as[i][2] + bf2f(bv4.z)) * cv.z;
        const float p3 = exp2_fast(as[i][3] + bf2f(bv4.w)) * cv.w;
        rloc[i] += (p0 + p1) + (p2 + p3);
        uint2 pw;
        pw.x = cvt_pk_bf16(p0, p1);
        pw.y = cvt_pk_bf16(p2, p3);
        *(uint2*)&BmPt[srow][scol] = pw;
      }
    }
    __syncthreads();   // P visible

    // ---- PV ----
#pragma unroll
    for (int kc = 0; kc < 4; ++kc) {
      short8 ap = *(const short8*)&BmPt[16 * w + r16][kc * 32 + g * 8];
#pragma unroll
      for (int j = 0; j < 4; ++j) {
        short8 bv = *(const short8*)&VtT[16 * j + r16][kc * 32 + g * 8];
        aco[j] = MFMA_BF16(ap, bv, aco[j], 0, 0, 0);
      }
    }
  }

#pragma unroll
  for (int i = 0; i < 4; ++i) {
    float vsum = rloc[i];
    vsum += __shfl_xor(vsum, 16);
    vsum += __shfl_xor(vsum, 32);
    if (l < 16) Rp[w][16 * i + r16] = vsum;
  }
  __syncthreads();

#pragma unroll
  for (int j = 0; j < 4; ++j)
#pragma unroll
    for (int r = 0; r < 4; ++r) {
      const int tl = 16 * w + 4 * g + r;
      const float R = Rp[0][tl] + Rp[1][tl] + Rp[2][tl] + Rp[3][tl];
      const float o = aco[j][r] / (R + EPSV);
      const int d = 16 * j + r16;
      O[((size_t)(b * 1024) + t0 + tl) * D_ + h * DH_ + d] = f2bf(o);
    }
}

// ---------------------------------------------------------------------------
extern "C" void kernel_launch(void* const* d_in, const int* in_sizes, int n_in,
                              void* d_out, int out_size, void* d_ws, size_t ws_size,
                              hipStream_t stream) {
  (void)in_sizes; (void)n_in; (void)out_size; (void)ws_size;
  const float* q    = (const float*)d_in[0];
  const float* k    = (const float*)d_in[1];
  const float* v    = (const float*)d_in[2];
  const int*   mask = (const int*)d_in[3];
  const float* bias = (const float*)d_in[4];
  const float* Wq   = (const float*)d_in[5];
  const float* Wk   = (const float*)d_in[6];
  const float* Wv   = (const float*)d_in[7];
  const float* Wo   = (const float*)d_in[8];
  float* out = (float*)d_out;

  ushort* qb   = (ushort*)d_ws;
  ushort* kb   = qb + 4194304;
  ushort* vb   = kb + 4194304;
  ushort* Wqb  = vb + 4194304;
  ushort* Wkb  = Wqb + 1048576;
  ushort* Wvb  = Wkb + 1048576;
  ushort* Wob  = Wvb + 1048576;
  ushort* Qh   = Wob + 1048576;
  ushort* Kh   = Qh + 4194304;
  ushort* VhT  = Kh + 4194304;
  ushort* Ob   = VhT + 4194304;
  ushort* bm   = Ob + 4194304;
  float*  pc   = (float*)(bm + 16777216);
  float*  Civ  = pc + 524288;

  k_prep<<<24576, 256, 0, stream>>>(q, k, v, Wq, Wk, Wv, Wo, bias, mask,
                                    qb, kb, vb, Wqb, Wkb, Wvb, Wob, bm);

  k_gemm<1><<<dim3(32, 8), 256, 0, stream>>>(qb, Wqb, Qh, SCALE_Q);
  k_gemm<1><<<dim3(32, 8), 256, 0, stream>>>(kb, Wkb, Kh, 1.0f);
  k_gemm<2><<<dim3(32, 8), 256, 0, stream>>>(vb, Wvb, VhT, 1.0f);

  k_colstats<<<dim3(8, 8, 64), 256, 0, stream>>>(Qh, Kh, bm, pc);
  k_combine<<<4096, 128, 0, stream>>>(pc, Civ);
  k_attn<<<1024, 256, 0, stream>>>(Qh, Kh, VhT, bm, Civ, Ob);

  k_gemm<0><<<dim3(32, 8), 256, 0, stream>>>(Ob, Wob, out, 1.0f);
}

// Round 13
// 194.511 us; speedup vs baseline: 1.0765x; 1.0765x over previous
//
#include <hip/hip_runtime.h>
#include <hip/hip_bf16.h>
#include <math.h>
#include <stdint.h>

#define B_ 4
#define T_ 1024
#define S_ 1024
#define D_ 1024
#define H_ 16
#define DH_ 64

static constexpr float EPSV = 1e-5f;
static constexpr float LOG2E = 1.4426950408889634f;
static constexpr float NEG2 = -1.4426950e9f;        // -1e9 * log2e
static constexpr float SCALE_Q = 0.125f * LOG2E;    // DH^-0.5 * log2e

typedef __attribute__((ext_vector_type(8))) short short8;
typedef __attribute__((ext_vector_type(4))) float f32x4;

#define MFMA_BF16 __builtin_amdgcn_mfma_f32_16x16x32_bf16

__device__ __forceinline__ ushort f2bf(float f) {
  union { float f; unsigned u; } v; v.f = f;
  unsigned r = (v.u + 0x7FFFu + ((v.u >> 16) & 1u)) >> 16;
  return (ushort)r;
}
__device__ __forceinline__ float bf2f(ushort u) {
  union { unsigned u; float f; } v; v.u = (unsigned)u << 16;
  return v.f;
}
// raw v_exp_f32: computes 2^x in one VALU op
__device__ __forceinline__ float exp2_fast(float x) {
  float r;
  asm("v_exp_f32 %0, %1" : "=v"(r) : "v"(x));
  return r;
}
// pack two f32 -> two bf16 (RNE) in one op
__device__ __forceinline__ unsigned cvt_pk_bf16(float lo, float hi) {
  unsigned r;
  asm("v_cvt_pk_bf16_f32 %0, %1, %2" : "=v"(r) : "v"(lo), "v"(hi));
  return r;
}

// async global->LDS, 16B per lane, wave-uniform LDS base + lane*16
__device__ __forceinline__ void gl_lds16(const ushort* g, ushort* l) {
  __builtin_amdgcn_global_load_lds(
      (const __attribute__((address_space(1))) unsigned int*)g,
      (__attribute__((address_space(3))) unsigned int*)l, 16, 0, 0);
}

// ---------------------------------------------------------------------------
// Fused prep: q/k/v converts [0,12288), weight converts [12288,16384),
// biasm = (mask ? -1e9 : bias) * log2e as bf16 [16384,24576).
// ---------------------------------------------------------------------------
__global__ __launch_bounds__(256) void k_prep(
    const float* __restrict__ q, const float* __restrict__ k,
    const float* __restrict__ v, const float* __restrict__ Wq,
    const float* __restrict__ Wk, const float* __restrict__ Wv,
    const float* __restrict__ Wo, const float* __restrict__ bias,
    const int* __restrict__ mask, ushort* __restrict__ qb,
    ushort* __restrict__ kb, ushort* __restrict__ vb,
    ushort* __restrict__ Wqb, ushort* __restrict__ Wkb,
    ushort* __restrict__ Wvb, ushort* __restrict__ Wob,
    ushort* __restrict__ bm) {
  const int bid = blockIdx.x;
  if (bid < 12288) {
    const int which = bid >> 12, local = bid & 4095;
    const float* src = (which == 0) ? q : (which == 1) ? k : v;
    ushort* dst = (which == 0) ? qb : (which == 1) ? kb : vb;
    const int i = (local * 256 + threadIdx.x) * 4;
    float4 t = *(const float4*)(src + i);
    *(ushort4*)(dst + i) = make_ushort4(f2bf(t.x), f2bf(t.y), f2bf(t.z), f2bf(t.w));
  } else if (bid < 16384) {
    const int wv_ = bid - 12288;
    const int which = wv_ >> 10, local = wv_ & 1023;
    const float* src = (which == 0) ? Wq : (which == 1) ? Wk : (which == 2) ? Wv : Wo;
    ushort* dst = (which == 0) ? Wqb : (which == 1) ? Wkb : (which == 2) ? Wvb : Wob;
    const int i = (local * 256 + threadIdx.x) * 4;
    float4 t = *(const float4*)(src + i);
    *(ushort4*)(dst + i) = make_ushort4(f2bf(t.x), f2bf(t.y), f2bf(t.z), f2bf(t.w));
  } else {
    const size_t i = ((size_t)(bid - 16384) * 256 + threadIdx.x) * 8;
    const size_t mi = i & (size_t)(T_ * S_ - 1);
    float4 b0 = *(const float4*)(bias + i);
    float4 b1 = *(const float4*)(bias + i + 4);
    int4 m0 = *(const int4*)(mask + mi);
    int4 m1 = *(const int4*)(mask + mi + 4);
    ushort o[8];
    o[0] = f2bf(m0.x ? NEG2 : b0.x * LOG2E); o[1] = f2bf(m0.y ? NEG2 : b0.y * LOG2E);
    o[2] = f2bf(m0.z ? NEG2 : b0.z * LOG2E); o[3] = f2bf(m0.w ? NEG2 : b0.w * LOG2E);
    o[4] = f2bf(m1.x ? NEG2 : b1.x * LOG2E); o[5] = f2bf(m1.y ? NEG2 : b1.y * LOG2E);
    o[6] = f2bf(m1.z ? NEG2 : b1.z * LOG2E); o[7] = f2bf(m1.w ? NEG2 : b1.w * LOG2E);
    *(uint4*)(bm + i) = *(uint4*)o;
  }
}

// ---------------------------------------------------------------------------
// bf16 MFMA GEMM: Y = A[4096,1024] @ W[1024,1024]^T.
// Staging via global_load_lds (width 16), linear [128][32] LDS tiles.
// MODE 0: f32 flat; MODE 1: bf16 head-split; MODE 2: bf16 head-split transposed.
// ---------------------------------------------------------------------------
template <int MODE>
__global__ __launch_bounds__(256) void k_gemm(const ushort* __restrict__ A,
                                              const ushort* __restrict__ W,
                                              void* __restrict__ Yv,
                                              float scale) {
  __shared__ ushort At[128][32];   // linear: required by global_load_lds
  __shared__ ushort Wt[128][32];
  const int tid = threadIdx.x;
  const int l = tid & 63, w = tid >> 6;
  const int wm = (w >> 1) * 64, wn = (w & 1) * 64;
  const int r16 = l & 15, g = l >> 4;
  const int i0 = blockIdx.x * 128, j0 = blockIdx.y * 128;
  const int srow = (l >> 2), scol = (l & 3) << 3;
  f32x4 acc[4][4] = {};

  for (int k0 = 0; k0 < D_; k0 += 32) {
    __syncthreads();
#pragma unroll
    for (int u = 0; u < 2; ++u) {
      const int row = w * 32 + u * 16 + srow;
      gl_lds16(&A[(size_t)(i0 + row) * D_ + k0 + scol], &At[w * 32 + u * 16][0]);
      gl_lds16(&W[(size_t)(j0 + row) * D_ + k0 + scol], &Wt[w * 32 + u * 16][0]);
    }
    __syncthreads();
    short8 a0[4], b0[4];
#pragma unroll
    for (int i = 0; i < 4; ++i) a0[i] = *(const short8*)&At[wm + 16 * i + r16][g * 8];
#pragma unroll
    for (int j = 0; j < 4; ++j) b0[j] = *(const short8*)&Wt[wn + 16 * j + r16][g * 8];
#pragma unroll
    for (int i = 0; i < 4; ++i)
#pragma unroll
      for (int j = 0; j < 4; ++j)
        acc[i][j] = MFMA_BF16(a0[i], b0[j], acc[i][j], 0, 0, 0);
  }

#pragma unroll
  for (int i = 0; i < 4; ++i)
#pragma unroll
    for (int j = 0; j < 4; ++j) {
      if (MODE == 2) {
        const int row0 = i0 + wm + 16 * i + 4 * g;
        const int col = j0 + wn + 16 * j + r16;
        const int bb = row0 >> 10, s = row0 & 1023;
        const int hh = col >> 6, dh = col & 63;
        ushort4 pw;
        pw.x = f2bf(acc[i][j][0] * scale); pw.y = f2bf(acc[i][j][1] * scale);
        pw.z = f2bf(acc[i][j][2] * scale); pw.w = f2bf(acc[i][j][3] * scale);
        *(ushort4*)&((ushort*)Yv)[((size_t)(bb * H_ + hh) * DH_ + dh) * 1024 + s] = pw;
      } else {
#pragma unroll
        for (int r = 0; r < 4; ++r) {
          const int row = i0 + wm + 16 * i + 4 * g + r;
          const int col = j0 + wn + 16 * j + r16;
          const float vv = acc[i][j][r] * scale;
          if (MODE == 0) {
            ((float*)Yv)[(size_t)row * D_ + col] = vv;
          } else {
            const int b = row >> 10, t = row & 1023;
            const int h = col >> 6, dh = col & 63;
            ((ushort*)Yv)[(((size_t)(b * H_ + h) * 1024) + t) * DH_ + dh] = f2bf(vv);
          }
        }
      }
    }
}

// ---------------------------------------------------------------------------
// Column sum-of-exp2 via MFMA. R11 internals; NEW: 1D XCD-local grid decode
// (4 batch-sharers of each bias tile dispatch-adjacent in one XCD slot) and
// T5 setprio around the MFMA cluster.
// ---------------------------------------------------------------------------
__global__ __launch_bounds__(256, 4) void k_colstats(const ushort* __restrict__ Qh,
                                                     const ushort* __restrict__ Kh,
                                                     const ushort* __restrict__ biasm,
                                                     float* __restrict__ pc) {
  __shared__ ushort Qt[128][72];
  __shared__ ushort U[9216];
  ushort (*Kt)[72] = (ushort(*)[72])U;
  typedef ushort Row144[144];
  Row144* Bm0 = (Row144*)U;
  Row144* Bm1 = (Row144*)(U + 4608);

  const int bid = blockIdx.x;
  const int x8 = bid & 7;
  const int b = (bid >> 3) & 3;
  const int v = (bid >> 5) * 8 + x8;       // [0,1024): (h, st, tt)
  const int h = v >> 6, st = (v >> 3) & 7, tt = v & 7;
  const int s0 = st * 128, t0 = tt * 128;
  const int tid = threadIdx.x, l = tid & 63, w = tid >> 6;
  const int r16 = l & 15, g = l >> 4;

  const ushort* qsrc = Qh + ((size_t)((b * H_ + h) * 1024) + t0) * DH_;
  const ushort* ksrc = Kh + ((size_t)((b * H_ + h) * 1024) + s0) * DH_;
#pragma unroll
  for (int u = 0; u < 4; ++u) {
    const int lin = u * 256 + tid;
    const int row = lin >> 3, c8 = (lin & 7) << 3;
    *(uint4*)&Qt[row][c8] = *(const uint4*)&qsrc[(size_t)row * DH_ + c8];
    *(uint4*)&Kt[row][c8] = *(const uint4*)&ksrc[(size_t)row * DH_ + c8];
  }
  __syncthreads();

  f32x4 acc[8][2] = {};
  __builtin_amdgcn_s_setprio(1);
#pragma unroll
  for (int kc = 0; kc < 2; ++kc) {
    short8 bk0 = *(const short8*)&Kt[w * 32 + r16][kc * 32 + g * 8];
    short8 bk1 = *(const short8*)&Kt[w * 32 + 16 + r16][kc * 32 + g * 8];
#pragma unroll
    for (int i = 0; i < 8; ++i) {
      short8 a = *(const short8*)&Qt[16 * i + r16][kc * 32 + g * 8];
      acc[i][0] = MFMA_BF16(a, bk0, acc[i][0], 0, 0, 0);
      acc[i][1] = MFMA_BF16(a, bk1, acc[i][1], 0, 0, 0);
    }
  }
  __builtin_amdgcn_s_setprio(0);
  __syncthreads();

  const ushort* bsrc = biasm + ((size_t)h * 1024 + t0) * 1024 + s0;
#pragma unroll
  for (int u = 0; u < 2; ++u) {
    const int lin = u * 256 + tid;
    const int row = lin >> 4, c8 = (lin & 15) << 3;
    *(uint4*)&Bm0[row][c8] = *(const uint4*)&bsrc[(size_t)row * 1024 + c8];
  }
  __syncthreads();

  float cs0 = 0.f, cs1 = 0.f;
  const int col0 = w * 32 + r16;
#pragma unroll
  for (int c = 0; c < 4; ++c) {
    Row144* cur = (c & 1) ? Bm1 : Bm0;
    if (c < 3) {
      Row144* nxt = (c & 1) ? Bm0 : Bm1;
#pragma unroll
      for (int u = 0; u < 2; ++u) {
        const int lin = u * 256 + tid;
        const int row = lin >> 4, c8 = (lin & 15) << 3;
        *(uint4*)&nxt[row][c8] =
            *(const uint4*)&bsrc[(size_t)((c + 1) * 32 + row) * 1024 + c8];
      }
    }
#pragma unroll
    for (int ii = 0; ii < 2; ++ii) {
      const int i = 2 * c + ii;
      const int lrow = 16 * ii + 4 * g;
#pragma unroll
      for (int r = 0; r < 4; ++r) {
        cs0 += exp2_fast(acc[i][0][r] + bf2f(cur[lrow + r][col0]));
        cs1 += exp2_fast(acc[i][1][r] + bf2f(cur[lrow + r][col0 + 16]));
      }
    }
    __syncthreads();
  }

  cs0 += __shfl_xor(cs0, 16); cs0 += __shfl_xor(cs0, 32);
  cs1 += __shfl_xor(cs1, 16); cs1 += __shfl_xor(cs1, 32);
  if (g == 0) {
    const size_t base = ((size_t)b * 1024 + s0 + col0) * 128 + h * 8 + tt;
    pc[base] = cs0;
    pc[base + 16 * 128] = cs1;
  }
}

// ---------------------------------------------------------------------------
// Combine 128 partial sums per (b,s) -> Civ = 1/C (R7 version).
// ---------------------------------------------------------------------------
__global__ __launch_bounds__(128) void k_combine(const float* __restrict__ pc,
                                                 float* __restrict__ Civ) {
  const int bs = blockIdx.x, tid = threadIdx.x;
  float c = pc[(size_t)bs * 128 + tid];
  __shared__ float sc[128];
  sc[tid] = c;
  __syncthreads();
  for (int off = 64; off > 0; off >>= 1) {
    if (tid < off) sc[tid] += sc[tid + off];
    __syncthreads();
  }
  if (tid == 0) {
    const float C = sc[0];
    Civ[bs] = (C > 0.f) ? 1.f / C : 0.f;
  }
}

// ---------------------------------------------------------------------------
// Attention pass (R13): R11 structure (LDS-staged K/V/bias, XCD-local decode)
// + T5 setprio around QK and PV MFMA clusters.
// ---------------------------------------------------------------------------
__global__ __launch_bounds__(256, 3) void k_attn(const ushort* __restrict__ Qh,
                                                 const ushort* __restrict__ Kh,
                                                 const ushort* __restrict__ VhT,
                                                 const ushort* __restrict__ biasm,
                                                 const float* __restrict__ Civ,
                                                 ushort* __restrict__ O) {
  __shared__ ushort Kt[128][68];     // 17408 B  (s rows of K chunk)
  __shared__ ushort VtT[64][132];    // 16896 B  (d rows, s cols)
  __shared__ ushort BmPt[64][132];   // 16896 B  (t rows, s cols; bias then P)
  __shared__ float Cih[128];
  __shared__ float Rp[4][64];

  const int bid = blockIdx.x;
  const int tt = bid >> 6;           // t-tile (16)
  const int bh = bid & 63;           // XCD = bh % 8 for all tt
  const int b = bh >> 4, h = bh & 15;
  const int t0 = tt * 64;

  const int tid = threadIdx.x, l = tid & 63, w = tid >> 6;
  const int r16 = l & 15, g = l >> 4;
  const size_t kvbase = (size_t)bh * 1024 * DH_;
  const size_t vbase  = (size_t)bh * DH_ * 1024;

  short8 aq[4][2];
#pragma unroll
  for (int i = 0; i < 4; ++i) {
    const ushort* qr = Qh + ((size_t)bh * 1024 + t0 + 16 * i + r16) * DH_;
    aq[i][0] = *(const short8*)(qr + g * 8);
    aq[i][1] = *(const short8*)(qr + 32 + g * 8);
  }

  f32x4 aco[4] = {};
  float rloc[4] = {};

#pragma unroll 1
  for (int sc = 0; sc < 8; ++sc) {
    const int s0c = sc * 128;
    __syncthreads();

    {
      const ushort* ksrc = Kh + kvbase + (size_t)s0c * DH_;
#pragma unroll
      for (int u = 0; u < 4; ++u) {
        const int lin = u * 256 + tid;
        const int row = lin >> 3, c8 = (lin & 7) << 3;
        *(uint4*)&Kt[row][c8] = *(const uint4*)&ksrc[(size_t)row * DH_ + c8];
      }
      const ushort* vsrc = VhT + vbase + s0c;
      const ushort* bsrc = biasm + ((size_t)h * 1024 + t0) * 1024 + s0c;
#pragma unroll
      for (int u = 0; u < 4; ++u) {
        const int lin = u * 256 + tid;
        const int row = lin >> 4, c8 = (lin & 15) << 3;
        *(uint4*)&VtT[row][c8] = *(const uint4*)&vsrc[(size_t)row * 1024 + c8];
        *(uint4*)&BmPt[row][c8] = *(const uint4*)&bsrc[(size_t)row * 1024 + c8];
      }
      if (tid < 128) Cih[tid] = Civ[(size_t)b * 1024 + s0c + tid];
    }
    __syncthreads();

#pragma unroll
    for (int j2 = 0; j2 < 2; ++j2) {
      const int jf = 2 * w + j2;
      f32x4 as[4] = {};
      short8 kf0 = *(const short8*)&Kt[16 * jf + r16][g * 8];
      short8 kf1 = *(const short8*)&Kt[16 * jf + r16][32 + g * 8];
      __builtin_amdgcn_s_setprio(1);
#pragma unroll
      for (int i = 0; i < 4; ++i) {
        as[i] = MFMA_BF16(kf0, aq[i][0], as[i], 0, 0, 0);
        as[i] = MFMA_BF16(kf1, aq[i][1], as[i], 0, 0, 0);
      }
      __builtin_amdgcn_s_setprio(0);
      const int scol = 16 * jf + 4 * g;
      const float4 cv = *(const float4*)&Cih[scol];
#pragma unroll
      for (int i = 0; i < 4; ++i) {
        const int srow = 16 * i + r16;
        ushort4 bv4 = *(const ushort4*)&BmPt[srow][scol];
        const float p0 = exp2_fast(as[i][0] + bf2f(bv4.x)) * cv.x;
        const float p1 = exp2_fast(as[i][1] + bf2f(bv4.y)) * cv.y;
        const float p2 = exp2_fast(as[i][2] + bf2f(bv4.z)) * cv.z;
        const float p3 = exp2_fast(as[i][3] + bf2f(bv4.w)) * cv.w;
        rloc[i] += (p0 + p1) + (p2 + p3);
        uint2 pw;
        pw.x = cvt_pk_bf16(p0, p1);
        pw.y = cvt_pk_bf16(p2, p3);
        *(uint2*)&BmPt[srow][scol] = pw;
      }
    }
    __syncthreads();

    __builtin_amdgcn_s_setprio(1);
#pragma unroll
    for (int kc = 0; kc < 4; ++kc) {
      short8 ap = *(const short8*)&BmPt[16 * w + r16][kc * 32 + g * 8];
#pragma unroll
      for (int j = 0; j < 4; ++j) {
        short8 bv = *(const short8*)&VtT[16 * j + r16][kc * 32 + g * 8];
        aco[j] = MFMA_BF16(ap, bv, aco[j], 0, 0, 0);
      }
    }
    __builtin_amdgcn_s_setprio(0);
  }

#pragma unroll
  for (int i = 0; i < 4; ++i) {
    float vsum = rloc[i];
    vsum += __shfl_xor(vsum, 16);
    vsum += __shfl_xor(vsum, 32);
    if (l < 16) Rp[w][16 * i + r16] = vsum;
  }
  __syncthreads();

#pragma unroll
  for (int j = 0; j < 4; ++j)
#pragma unroll
    for (int r = 0; r < 4; ++r) {
      const int tl = 16 * w + 4 * g + r;
      const float R = Rp[0][tl] + Rp[1][tl] + Rp[2][tl] + Rp[3][tl];
      const float o = aco[j][r] / (R + EPSV);
      const int d = 16 * j + r16;
      O[((size_t)(b * 1024) + t0 + tl) * D_ + h * DH_ + d] = f2bf(o);
    }
}

// ---------------------------------------------------------------------------
extern "C" void kernel_launch(void* const* d_in, const int* in_sizes, int n_in,
                              void* d_out, int out_size, void* d_ws, size_t ws_size,
                              hipStream_t stream) {
  (void)in_sizes; (void)n_in; (void)out_size; (void)ws_size;
  const float* q    = (const float*)d_in[0];
  const float* k    = (const float*)d_in[1];
  const float* v    = (const float*)d_in[2];
  const int*   mask = (const int*)d_in[3];
  const float* bias = (const float*)d_in[4];
  const float* Wq   = (const float*)d_in[5];
  const float* Wk   = (const float*)d_in[6];
  const float* Wv   = (const float*)d_in[7];
  const float* Wo   = (const float*)d_in[8];
  float* out = (float*)d_out;

  ushort* qb   = (ushort*)d_ws;
  ushort* kb   = qb + 4194304;
  ushort* vb   = kb + 4194304;
  ushort* Wqb  = vb + 4194304;
  ushort* Wkb  = Wqb + 1048576;
  ushort* Wvb  = Wkb + 1048576;
  ushort* Wob  = Wvb + 1048576;
  ushort* Qh   = Wob + 1048576;
  ushort* Kh   = Qh + 4194304;
  ushort* VhT  = Kh + 4194304;
  ushort* Ob   = VhT + 4194304;
  ushort* bm   = Ob + 4194304;
  float*  pc   = (float*)(bm + 16777216);
  float*  Civ  = pc + 524288;

  k_prep<<<24576, 256, 0, stream>>>(q, k, v, Wq, Wk, Wv, Wo, bias, mask,
                                    qb, kb, vb, Wqb, Wkb, Wvb, Wob, bm);

  k_gemm<1><<<dim3(32, 8), 256, 0, stream>>>(qb, Wqb, Qh, SCALE_Q);
  k_gemm<1><<<dim3(32, 8), 256, 0, stream>>>(kb, Wkb, Kh, 1.0f);
  k_gemm<2><<<dim3(32, 8), 256, 0, stream>>>(vb, Wvb, VhT, 1.0f);

  k_colstats<<<4096, 256, 0, stream>>>(Qh, Kh, bm, pc);
  k_combine<<<4096, 128, 0, stream>>>(pc, Civ);
  k_attn<<<1024, 256, 0, stream>>>(Qh, Kh, VhT, bm, Civ, Ob);

  k_gemm<0><<<dim3(32, 8), 256, 0, stream>>>(Ob, Wob, out, 1.0f);
}

// Round 14
// 191.175 us; speedup vs baseline: 1.0953x; 1.0175x over previous
//
#include <hip/hip_runtime.h>
#include <hip/hip_bf16.h>
#include <math.h>
#include <stdint.h>

#define B_ 4
#define T_ 1024
#define S_ 1024
#define D_ 1024
#define H_ 16
#define DH_ 64

static constexpr float EPSV = 1e-5f;
static constexpr float LOG2E = 1.4426950408889634f;
static constexpr float NEG2 = -1.4426950e9f;        // -1e9 * log2e
static constexpr float SCALE_Q = 0.125f * LOG2E;    // DH^-0.5 * log2e

typedef __attribute__((ext_vector_type(8))) short short8;
typedef __attribute__((ext_vector_type(4))) float f32x4;

#define MFMA_BF16 __builtin_amdgcn_mfma_f32_16x16x32_bf16

__device__ __forceinline__ ushort f2bf(float f) {
  union { float f; unsigned u; } v; v.f = f;
  unsigned r = (v.u + 0x7FFFu + ((v.u >> 16) & 1u)) >> 16;
  return (ushort)r;
}
__device__ __forceinline__ float bf2f(ushort u) {
  union { unsigned u; float f; } v; v.u = (unsigned)u << 16;
  return v.f;
}
// raw v_exp_f32: computes 2^x in one VALU op
__device__ __forceinline__ float exp2_fast(float x) {
  float r;
  asm("v_exp_f32 %0, %1" : "=v"(r) : "v"(x));
  return r;
}
// pack two f32 -> two bf16 (RNE) in one op
__device__ __forceinline__ unsigned cvt_pk_bf16(float lo, float hi) {
  unsigned r;
  asm("v_cvt_pk_bf16_f32 %0, %1, %2" : "=v"(r) : "v"(lo), "v"(hi));
  return r;
}

// async global->LDS, 16B per lane, wave-uniform LDS base + lane*16
__device__ __forceinline__ void gl_lds16(const ushort* g, ushort* l) {
  __builtin_amdgcn_global_load_lds(
      (const __attribute__((address_space(1))) unsigned int*)g,
      (__attribute__((address_space(3))) unsigned int*)l, 16, 0, 0);
}

// ---------------------------------------------------------------------------
// Fused prep: q/k/v converts [0,12288), weight converts [12288,16384),
// biasm = (mask ? -1e9 : bias) * log2e as bf16 [16384,24576).
// ---------------------------------------------------------------------------
__global__ __launch_bounds__(256) void k_prep(
    const float* __restrict__ q, const float* __restrict__ k,
    const float* __restrict__ v, const float* __restrict__ Wq,
    const float* __restrict__ Wk, const float* __restrict__ Wv,
    const float* __restrict__ Wo, const float* __restrict__ bias,
    const int* __restrict__ mask, ushort* __restrict__ qb,
    ushort* __restrict__ kb, ushort* __restrict__ vb,
    ushort* __restrict__ Wqb, ushort* __restrict__ Wkb,
    ushort* __restrict__ Wvb, ushort* __restrict__ Wob,
    ushort* __restrict__ bm) {
  const int bid = blockIdx.x;
  if (bid < 12288) {
    const int which = bid >> 12, local = bid & 4095;
    const float* src = (which == 0) ? q : (which == 1) ? k : v;
    ushort* dst = (which == 0) ? qb : (which == 1) ? kb : vb;
    const int i = (local * 256 + threadIdx.x) * 4;
    float4 t = *(const float4*)(src + i);
    *(ushort4*)(dst + i) = make_ushort4(f2bf(t.x), f2bf(t.y), f2bf(t.z), f2bf(t.w));
  } else if (bid < 16384) {
    const int wv_ = bid - 12288;
    const int which = wv_ >> 10, local = wv_ & 1023;
    const float* src = (which == 0) ? Wq : (which == 1) ? Wk : (which == 2) ? Wv : Wo;
    ushort* dst = (which == 0) ? Wqb : (which == 1) ? Wkb : (which == 2) ? Wvb : Wob;
    const int i = (local * 256 + threadIdx.x) * 4;
    float4 t = *(const float4*)(src + i);
    *(ushort4*)(dst + i) = make_ushort4(f2bf(t.x), f2bf(t.y), f2bf(t.z), f2bf(t.w));
  } else {
    const size_t i = ((size_t)(bid - 16384) * 256 + threadIdx.x) * 8;
    const size_t mi = i & (size_t)(T_ * S_ - 1);
    float4 b0 = *(const float4*)(bias + i);
    float4 b1 = *(const float4*)(bias + i + 4);
    int4 m0 = *(const int4*)(mask + mi);
    int4 m1 = *(const int4*)(mask + mi + 4);
    ushort o[8];
    o[0] = f2bf(m0.x ? NEG2 : b0.x * LOG2E); o[1] = f2bf(m0.y ? NEG2 : b0.y * LOG2E);
    o[2] = f2bf(m0.z ? NEG2 : b0.z * LOG2E); o[3] = f2bf(m0.w ? NEG2 : b0.w * LOG2E);
    o[4] = f2bf(m1.x ? NEG2 : b1.x * LOG2E); o[5] = f2bf(m1.y ? NEG2 : b1.y * LOG2E);
    o[6] = f2bf(m1.z ? NEG2 : b1.z * LOG2E); o[7] = f2bf(m1.w ? NEG2 : b1.w * LOG2E);
    *(uint4*)(bm + i) = *(uint4*)o;
  }
}

// ---------------------------------------------------------------------------
// bf16 MFMA GEMM: Y = A[4096,1024] @ W[1024,1024]^T.
// Staging via global_load_lds (width 16), linear [128][32] LDS tiles.
// MODE 0: f32 flat; MODE 1: bf16 head-split; MODE 2: bf16 head-split transposed.
// ---------------------------------------------------------------------------
template <int MODE>
__global__ __launch_bounds__(256) void k_gemm(const ushort* __restrict__ A,
                                              const ushort* __restrict__ W,
                                              void* __restrict__ Yv,
                                              float scale) {
  __shared__ ushort At[128][32];   // linear: required by global_load_lds
  __shared__ ushort Wt[128][32];
  const int tid = threadIdx.x;
  const int l = tid & 63, w = tid >> 6;
  const int wm = (w >> 1) * 64, wn = (w & 1) * 64;
  const int r16 = l & 15, g = l >> 4;
  const int i0 = blockIdx.x * 128, j0 = blockIdx.y * 128;
  const int srow = (l >> 2), scol = (l & 3) << 3;
  f32x4 acc[4][4] = {};

  for (int k0 = 0; k0 < D_; k0 += 32) {
    __syncthreads();
#pragma unroll
    for (int u = 0; u < 2; ++u) {
      const int row = w * 32 + u * 16 + srow;
      gl_lds16(&A[(size_t)(i0 + row) * D_ + k0 + scol], &At[w * 32 + u * 16][0]);
      gl_lds16(&W[(size_t)(j0 + row) * D_ + k0 + scol], &Wt[w * 32 + u * 16][0]);
    }
    __syncthreads();
    short8 a0[4], b0[4];
#pragma unroll
    for (int i = 0; i < 4; ++i) a0[i] = *(const short8*)&At[wm + 16 * i + r16][g * 8];
#pragma unroll
    for (int j = 0; j < 4; ++j) b0[j] = *(const short8*)&Wt[wn + 16 * j + r16][g * 8];
#pragma unroll
    for (int i = 0; i < 4; ++i)
#pragma unroll
      for (int j = 0; j < 4; ++j)
        acc[i][j] = MFMA_BF16(a0[i], b0[j], acc[i][j], 0, 0, 0);
  }

#pragma unroll
  for (int i = 0; i < 4; ++i)
#pragma unroll
    for (int j = 0; j < 4; ++j) {
      if (MODE == 2) {
        const int row0 = i0 + wm + 16 * i + 4 * g;
        const int col = j0 + wn + 16 * j + r16;
        const int bb = row0 >> 10, s = row0 & 1023;
        const int hh = col >> 6, dh = col & 63;
        ushort4 pw;
        pw.x = f2bf(acc[i][j][0] * scale); pw.y = f2bf(acc[i][j][1] * scale);
        pw.z = f2bf(acc[i][j][2] * scale); pw.w = f2bf(acc[i][j][3] * scale);
        *(ushort4*)&((ushort*)Yv)[((size_t)(bb * H_ + hh) * DH_ + dh) * 1024 + s] = pw;
      } else {
#pragma unroll
        for (int r = 0; r < 4; ++r) {
          const int row = i0 + wm + 16 * i + 4 * g + r;
          const int col = j0 + wn + 16 * j + r16;
          const float vv = acc[i][j][r] * scale;
          if (MODE == 0) {
            ((float*)Yv)[(size_t)row * D_ + col] = vv;
          } else {
            const int b = row >> 10, t = row & 1023;
            const int h = col >> 6, dh = col & 63;
            ((ushort*)Yv)[(((size_t)(b * H_ + h) * 1024) + t) * DH_ + dh] = f2bf(vv);
          }
        }
      }
    }
}

// ---------------------------------------------------------------------------
// Column sum-of-exp2 via MFMA (R13 version, unchanged).
// ---------------------------------------------------------------------------
__global__ __launch_bounds__(256, 4) void k_colstats(const ushort* __restrict__ Qh,
                                                     const ushort* __restrict__ Kh,
                                                     const ushort* __restrict__ biasm,
                                                     float* __restrict__ pc) {
  __shared__ ushort Qt[128][72];
  __shared__ ushort U[9216];
  ushort (*Kt)[72] = (ushort(*)[72])U;
  typedef ushort Row144[144];
  Row144* Bm0 = (Row144*)U;
  Row144* Bm1 = (Row144*)(U + 4608);

  const int bid = blockIdx.x;
  const int x8 = bid & 7;
  const int b = (bid >> 3) & 3;
  const int v = (bid >> 5) * 8 + x8;       // [0,1024): (h, st, tt)
  const int h = v >> 6, st = (v >> 3) & 7, tt = v & 7;
  const int s0 = st * 128, t0 = tt * 128;
  const int tid = threadIdx.x, l = tid & 63, w = tid >> 6;
  const int r16 = l & 15, g = l >> 4;

  const ushort* qsrc = Qh + ((size_t)((b * H_ + h) * 1024) + t0) * DH_;
  const ushort* ksrc = Kh + ((size_t)((b * H_ + h) * 1024) + s0) * DH_;
#pragma unroll
  for (int u = 0; u < 4; ++u) {
    const int lin = u * 256 + tid;
    const int row = lin >> 3, c8 = (lin & 7) << 3;
    *(uint4*)&Qt[row][c8] = *(const uint4*)&qsrc[(size_t)row * DH_ + c8];
    *(uint4*)&Kt[row][c8] = *(const uint4*)&ksrc[(size_t)row * DH_ + c8];
  }
  __syncthreads();

  f32x4 acc[8][2] = {};
  __builtin_amdgcn_s_setprio(1);
#pragma unroll
  for (int kc = 0; kc < 2; ++kc) {
    short8 bk0 = *(const short8*)&Kt[w * 32 + r16][kc * 32 + g * 8];
    short8 bk1 = *(const short8*)&Kt[w * 32 + 16 + r16][kc * 32 + g * 8];
#pragma unroll
    for (int i = 0; i < 8; ++i) {
      short8 a = *(const short8*)&Qt[16 * i + r16][kc * 32 + g * 8];
      acc[i][0] = MFMA_BF16(a, bk0, acc[i][0], 0, 0, 0);
      acc[i][1] = MFMA_BF16(a, bk1, acc[i][1], 0, 0, 0);
    }
  }
  __builtin_amdgcn_s_setprio(0);
  __syncthreads();

  const ushort* bsrc = biasm + ((size_t)h * 1024 + t0) * 1024 + s0;
#pragma unroll
  for (int u = 0; u < 2; ++u) {
    const int lin = u * 256 + tid;
    const int row = lin >> 4, c8 = (lin & 15) << 3;
    *(uint4*)&Bm0[row][c8] = *(const uint4*)&bsrc[(size_t)row * 1024 + c8];
  }
  __syncthreads();

  float cs0 = 0.f, cs1 = 0.f;
  const int col0 = w * 32 + r16;
#pragma unroll
  for (int c = 0; c < 4; ++c) {
    Row144* cur = (c & 1) ? Bm1 : Bm0;
    if (c < 3) {
      Row144* nxt = (c & 1) ? Bm0 : Bm1;
#pragma unroll
      for (int u = 0; u < 2; ++u) {
        const int lin = u * 256 + tid;
        const int row = lin >> 4, c8 = (lin & 15) << 3;
        *(uint4*)&nxt[row][c8] =
            *(const uint4*)&bsrc[(size_t)((c + 1) * 32 + row) * 1024 + c8];
      }
    }
#pragma unroll
    for (int ii = 0; ii < 2; ++ii) {
      const int i = 2 * c + ii;
      const int lrow = 16 * ii + 4 * g;
#pragma unroll
      for (int r = 0; r < 4; ++r) {
        cs0 += exp2_fast(acc[i][0][r] + bf2f(cur[lrow + r][col0]));
        cs1 += exp2_fast(acc[i][1][r] + bf2f(cur[lrow + r][col0 + 16]));
      }
    }
    __syncthreads();
  }

  cs0 += __shfl_xor(cs0, 16); cs0 += __shfl_xor(cs0, 32);
  cs1 += __shfl_xor(cs1, 16); cs1 += __shfl_xor(cs1, 32);
  if (g == 0) {
    const size_t base = ((size_t)b * 1024 + s0 + col0) * 128 + h * 8 + tt;
    pc[base] = cs0;
    pc[base + 16 * 128] = cs1;
  }
}

// ---------------------------------------------------------------------------
// Combine 128 partial sums per (b,s) -> Civ = 1/C.
// ---------------------------------------------------------------------------
__global__ __launch_bounds__(128) void k_combine(const float* __restrict__ pc,
                                                 float* __restrict__ Civ) {
  const int bs = blockIdx.x, tid = threadIdx.x;
  float c = pc[(size_t)bs * 128 + tid];
  __shared__ float sc[128];
  sc[tid] = c;
  __syncthreads();
  for (int off = 64; off > 0; off >>= 1) {
    if (tid < off) sc[tid] += sc[tid + off];
    __syncthreads();
  }
  if (tid == 0) {
    const float C = sc[0];
    Civ[bs] = (C > 0.f) ? 1.f / C : 0.f;
  }
}

// ---------------------------------------------------------------------------
// Attention pass (R14): t-tile DOUBLED to 128 rows. Grid 512 = exactly
// 2 blocks/CU (LDS 70.7 KB) -> one fully-resident round, no tail; 2x work
// per barrier. Same 3-barrier chunk loop, swapped QK, exp2+cvt_pk, XCD-local
// decode (all 8 t-tiles of a bh on XCD bh%8).
// ---------------------------------------------------------------------------
__global__ __launch_bounds__(256, 2) void k_attn(const ushort* __restrict__ Qh,
                                                 const ushort* __restrict__ Kh,
                                                 const ushort* __restrict__ VhT,
                                                 const ushort* __restrict__ biasm,
                                                 const float* __restrict__ Civ,
                                                 ushort* __restrict__ O) {
  __shared__ ushort Kt[128][68];     // 17408 B  (s rows of K chunk)
  __shared__ ushort VtT[64][132];    // 16896 B  (d rows, s cols)
  __shared__ ushort BmPt[128][132];  // 33792 B  (t rows, s cols; bias then P)
  __shared__ float Cih[128];
  __shared__ float Rp[4][128];

  const int bid = blockIdx.x;
  const int tt = bid >> 6;           // t-tile (8 of 128 rows)
  const int bh = bid & 63;           // XCD = bh % 8 for all tt
  const int b = bh >> 4, h = bh & 15;
  const int t0 = tt * 128;

  const int tid = threadIdx.x, l = tid & 63, w = tid >> 6;
  const int r16 = l & 15, g = l >> 4;
  const size_t kvbase = (size_t)bh * 1024 * DH_;
  const size_t vbase  = (size_t)bh * DH_ * 1024;

  short8 aq[8][2];
#pragma unroll
  for (int i = 0; i < 8; ++i) {
    const ushort* qr = Qh + ((size_t)bh * 1024 + t0 + 16 * i + r16) * DH_;
    aq[i][0] = *(const short8*)(qr + g * 8);
    aq[i][1] = *(const short8*)(qr + 32 + g * 8);
  }

  f32x4 aco[2][4] = {};
  float rloc[8] = {};

#pragma unroll 1
  for (int sc = 0; sc < 8; ++sc) {
    const int s0c = sc * 128;
    __syncthreads();

    {
      const ushort* ksrc = Kh + kvbase + (size_t)s0c * DH_;
#pragma unroll
      for (int u = 0; u < 4; ++u) {
        const int lin = u * 256 + tid;
        const int row = lin >> 3, c8 = (lin & 7) << 3;
        *(uint4*)&Kt[row][c8] = *(const uint4*)&ksrc[(size_t)row * DH_ + c8];
      }
      const ushort* vsrc = VhT + vbase + s0c;
#pragma unroll
      for (int u = 0; u < 4; ++u) {
        const int lin = u * 256 + tid;
        const int row = lin >> 4, c8 = (lin & 15) << 3;
        *(uint4*)&VtT[row][c8] = *(const uint4*)&vsrc[(size_t)row * 1024 + c8];
      }
      const ushort* bsrc = biasm + ((size_t)h * 1024 + t0) * 1024 + s0c;
#pragma unroll
      for (int u = 0; u < 8; ++u) {
        const int lin = u * 256 + tid;
        const int row = lin >> 4, c8 = (lin & 15) << 3;
        *(uint4*)&BmPt[row][c8] = *(const uint4*)&bsrc[(size_t)row * 1024 + c8];
      }
      if (tid < 128) Cih[tid] = Civ[(size_t)b * 1024 + s0c + tid];
    }
    __syncthreads();

    // ---- QK (A = K from LDS, B = Q regs) + exp, per jf ----
#pragma unroll
    for (int j2 = 0; j2 < 2; ++j2) {
      const int jf = 2 * w + j2;
      f32x4 as[8] = {};
      short8 kf0 = *(const short8*)&Kt[16 * jf + r16][g * 8];
      short8 kf1 = *(const short8*)&Kt[16 * jf + r16][32 + g * 8];
      __builtin_amdgcn_s_setprio(1);
#pragma unroll
      for (int i = 0; i < 8; ++i) {
        as[i] = MFMA_BF16(kf0, aq[i][0], as[i], 0, 0, 0);
        as[i] = MFMA_BF16(kf1, aq[i][1], as[i], 0, 0, 0);
      }
      __builtin_amdgcn_s_setprio(0);
      const int scol = 16 * jf + 4 * g;
      const float4 cv = *(const float4*)&Cih[scol];
#pragma unroll
      for (int i = 0; i < 8; ++i) {
        const int srow = 16 * i + r16;
        ushort4 bv4 = *(const ushort4*)&BmPt[srow][scol];
        const float p0 = exp2_fast(as[i][0] + bf2f(bv4.x)) * cv.x;
        const float p1 = exp2_fast(as[i][1] + bf2f(bv4.y)) * cv.y;
        const float p2 = exp2_fast(as[i][2] + bf2f(bv4.z)) * cv.z;
        const float p3 = exp2_fast(as[i][3] + bf2f(bv4.w)) * cv.w;
        rloc[i] += (p0 + p1) + (p2 + p3);
        uint2 pw;
        pw.x = cvt_pk_bf16(p0, p1);
        pw.y = cvt_pk_bf16(p2, p3);
        *(uint2*)&BmPt[srow][scol] = pw;
      }
    }
    __syncthreads();

    // ---- PV: wave w owns t rows 32w..32w+31 (rg = 0,1) ----
    __builtin_amdgcn_s_setprio(1);
#pragma unroll
    for (int rg = 0; rg < 2; ++rg) {
#pragma unroll
      for (int kc = 0; kc < 4; ++kc) {
        short8 ap = *(const short8*)&BmPt[32 * w + 16 * rg + r16][kc * 32 + g * 8];
#pragma unroll
        for (int j = 0; j < 4; ++j) {
          short8 bv = *(const short8*)&VtT[16 * j + r16][kc * 32 + g * 8];
          aco[rg][j] = MFMA_BF16(ap, bv, aco[rg][j], 0, 0, 0);
        }
      }
    }
    __builtin_amdgcn_s_setprio(0);
  }

  // row sums: reduce over g-lanes (xor 16, 32), then across waves via Rp
#pragma unroll
  for (int i = 0; i < 8; ++i) {
    float vsum = rloc[i];
    vsum += __shfl_xor(vsum, 16);
    vsum += __shfl_xor(vsum, 32);
    if (l < 16) Rp[w][16 * i + r16] = vsum;
  }
  __syncthreads();

#pragma unroll
  for (int rg = 0; rg < 2; ++rg)
#pragma unroll
    for (int j = 0; j < 4; ++j)
#pragma unroll
      for (int r = 0; r < 4; ++r) {
        const int tl = 32 * w + 16 * rg + 4 * g + r;
        const float R = Rp[0][tl] + Rp[1][tl] + Rp[2][tl] + Rp[3][tl];
        const float o = aco[rg][j][r] / (R + EPSV);
        const int d = 16 * j + r16;
        O[((size_t)(b * 1024) + t0 + tl) * D_ + h * DH_ + d] = f2bf(o);
      }
}

// ---------------------------------------------------------------------------
extern "C" void kernel_launch(void* const* d_in, const int* in_sizes, int n_in,
                              void* d_out, int out_size, void* d_ws, size_t ws_size,
                              hipStream_t stream) {
  (void)in_sizes; (void)n_in; (void)out_size; (void)ws_size;
  const float* q    = (const float*)d_in[0];
  const float* k    = (const float*)d_in[1];
  const float* v    = (const float*)d_in[2];
  const int*   mask = (const int*)d_in[3];
  const float* bias = (const float*)d_in[4];
  const float* Wq   = (const float*)d_in[5];
  const float* Wk   = (const float*)d_in[6];
  const float* Wv   = (const float*)d_in[7];
  const float* Wo   = (const float*)d_in[8];
  float* out = (float*)d_out;

  ushort* qb   = (ushort*)d_ws;
  ushort* kb   = qb + 4194304;
  ushort* vb   = kb + 4194304;
  ushort* Wqb  = vb + 4194304;
  ushort* Wkb  = Wqb + 1048576;
  ushort* Wvb  = Wkb + 1048576;
  ushort* Wob  = Wvb + 1048576;
  ushort* Qh   = Wob + 1048576;
  ushort* Kh   = Qh + 4194304;
  ushort* VhT  = Kh + 4194304;
  ushort* Ob   = VhT + 4194304;
  ushort* bm   = Ob + 4194304;
  float*  pc   = (float*)(bm + 16777216);
  float*  Civ  = pc + 524288;

  k_prep<<<24576, 256, 0, stream>>>(q, k, v, Wq, Wk, Wv, Wo, bias, mask,
                                    qb, kb, vb, Wqb, Wkb, Wvb, Wob, bm);

  k_gemm<1><<<dim3(32, 8), 256, 0, stream>>>(qb, Wqb, Qh, SCALE_Q);
  k_gemm<1><<<dim3(32, 8), 256, 0, stream>>>(kb, Wkb, Kh, 1.0f);
  k_gemm<2><<<dim3(32, 8), 256, 0, stream>>>(vb, Wvb, VhT, 1.0f);

  k_colstats<<<4096, 256, 0, stream>>>(Qh, Kh, bm, pc);
  k_combine<<<4096, 128, 0, stream>>>(pc, Civ);
  k_attn<<<512, 256, 0, stream>>>(Qh, Kh, VhT, bm, Civ, Ob);

  k_gemm<0><<<dim3(32, 8), 256, 0, stream>>>(Ob, Wob, out, 1.0f);
}

// Round 15
// 190.725 us; speedup vs baseline: 1.0979x; 1.0024x over previous
//
#include <hip/hip_runtime.h>
#include <hip/hip_bf16.h>
#include <math.h>
#include <stdint.h>

#define B_ 4
#define T_ 1024
#define S_ 1024
#define D_ 1024
#define H_ 16
#define DH_ 64

static constexpr float EPSV = 1e-5f;
static constexpr float LOG2E = 1.4426950408889634f;
static constexpr float NEG2 = -1.4426950e9f;        // -1e9 * log2e
static constexpr float SCALE_Q = 0.125f * LOG2E;    // DH^-0.5 * log2e

typedef __attribute__((ext_vector_type(8))) short short8;
typedef __attribute__((ext_vector_type(4))) float f32x4;

#define MFMA_BF16 __builtin_amdgcn_mfma_f32_16x16x32_bf16

__device__ __forceinline__ ushort f2bf(float f) {
  union { float f; unsigned u; } v; v.f = f;
  unsigned r = (v.u + 0x7FFFu + ((v.u >> 16) & 1u)) >> 16;
  return (ushort)r;
}
__device__ __forceinline__ float bf2f(ushort u) {
  union { unsigned u; float f; } v; v.u = (unsigned)u << 16;
  return v.f;
}
// raw v_exp_f32: computes 2^x in one VALU op
__device__ __forceinline__ float exp2_fast(float x) {
  float r;
  asm("v_exp_f32 %0, %1" : "=v"(r) : "v"(x));
  return r;
}
// pack two f32 -> two bf16 (RNE) in one op
__device__ __forceinline__ unsigned cvt_pk_bf16(float lo, float hi) {
  unsigned r;
  asm("v_cvt_pk_bf16_f32 %0, %1, %2" : "=v"(r) : "v"(lo), "v"(hi));
  return r;
}

// async global->LDS, 16B per lane, wave-uniform LDS base + lane*16
__device__ __forceinline__ void gl_lds16(const ushort* g, ushort* l) {
  __builtin_amdgcn_global_load_lds(
      (const __attribute__((address_space(1))) unsigned int*)g,
      (__attribute__((address_space(3))) unsigned int*)l, 16, 0, 0);
}

// ---------------------------------------------------------------------------
// Fused prep, MLP-optimized: each block moves 4096 elems in 4 block-strided
// chunks; each thread keeps 4-8 loads in flight before converting.
//   [0,3072):  q/k/v f32->bf16           (1024 blocks each)
//   [3072,4096): W f32->bf16             (256 blocks each)
//   [4096,8192): biasm = (mask?-1e9:bias)*log2e  (4096 blocks)
// ---------------------------------------------------------------------------
__global__ __launch_bounds__(256) void k_prep(
    const float* __restrict__ q, const float* __restrict__ k,
    const float* __restrict__ v, const float* __restrict__ Wq,
    const float* __restrict__ Wk, const float* __restrict__ Wv,
    const float* __restrict__ Wo, const float* __restrict__ bias,
    const int* __restrict__ mask, ushort* __restrict__ qb,
    ushort* __restrict__ kb, ushort* __restrict__ vb,
    ushort* __restrict__ Wqb, ushort* __restrict__ Wkb,
    ushort* __restrict__ Wvb, ushort* __restrict__ Wob,
    ushort* __restrict__ bm) {
  const int bid = blockIdx.x;
  const int tid = threadIdx.x;
  if (bid < 4096) {
    const float* src;
    ushort* dst;
    size_t base;
    if (bid < 3072) {
      const int which = bid >> 10, local = bid & 1023;
      src = (which == 0) ? q : (which == 1) ? k : v;
      dst = (which == 0) ? qb : (which == 1) ? kb : vb;
      base = (size_t)local * 4096 + tid * 4;
    } else {
      const int wv_ = bid - 3072;
      const int which = wv_ >> 8, local = wv_ & 255;
      src = (which == 0) ? Wq : (which == 1) ? Wk : (which == 2) ? Wv : Wo;
      dst = (which == 0) ? Wqb : (which == 1) ? Wkb : (which == 2) ? Wvb : Wob;
      base = (size_t)local * 4096 + tid * 4;
    }
    float4 f0 = *(const float4*)(src + base);
    float4 f1 = *(const float4*)(src + base + 1024);
    float4 f2 = *(const float4*)(src + base + 2048);
    float4 f3 = *(const float4*)(src + base + 3072);
    *(ushort4*)(dst + base)        = make_ushort4(f2bf(f0.x), f2bf(f0.y), f2bf(f0.z), f2bf(f0.w));
    *(ushort4*)(dst + base + 1024) = make_ushort4(f2bf(f1.x), f2bf(f1.y), f2bf(f1.z), f2bf(f1.w));
    *(ushort4*)(dst + base + 2048) = make_ushort4(f2bf(f2.x), f2bf(f2.y), f2bf(f2.z), f2bf(f2.w));
    *(ushort4*)(dst + base + 3072) = make_ushort4(f2bf(f3.x), f2bf(f3.y), f2bf(f3.z), f2bf(f3.w));
  } else {
    const int bb = bid - 4096;
    const size_t base = (size_t)bb * 4096 + tid * 4;
    const size_t mi0 = base & (size_t)(T_ * S_ - 1);
    float4 b0 = *(const float4*)(bias + base);
    float4 b1 = *(const float4*)(bias + base + 1024);
    float4 b2 = *(const float4*)(bias + base + 2048);
    float4 b3 = *(const float4*)(bias + base + 3072);
    int4 m0 = *(const int4*)(mask + mi0);
    int4 m1 = *(const int4*)(mask + mi0 + 1024);
    int4 m2 = *(const int4*)(mask + mi0 + 2048);
    int4 m3 = *(const int4*)(mask + mi0 + 3072);
    ushort4 o0 = make_ushort4(f2bf(m0.x ? NEG2 : b0.x * LOG2E),
                              f2bf(m0.y ? NEG2 : b0.y * LOG2E),
                              f2bf(m0.z ? NEG2 : b0.z * LOG2E),
                              f2bf(m0.w ? NEG2 : b0.w * LOG2E));
    ushort4 o1 = make_ushort4(f2bf(m1.x ? NEG2 : b1.x * LOG2E),
                              f2bf(m1.y ? NEG2 : b1.y * LOG2E),
                              f2bf(m1.z ? NEG2 : b1.z * LOG2E),
                              f2bf(m1.w ? NEG2 : b1.w * LOG2E));
    ushort4 o2 = make_ushort4(f2bf(m2.x ? NEG2 : b2.x * LOG2E),
                              f2bf(m2.y ? NEG2 : b2.y * LOG2E),
                              f2bf(m2.z ? NEG2 : b2.z * LOG2E),
                              f2bf(m2.w ? NEG2 : b2.w * LOG2E));
    ushort4 o3 = make_ushort4(f2bf(m3.x ? NEG2 : b3.x * LOG2E),
                              f2bf(m3.y ? NEG2 : b3.y * LOG2E),
                              f2bf(m3.z ? NEG2 : b3.z * LOG2E),
                              f2bf(m3.w ? NEG2 : b3.w * LOG2E));
    *(ushort4*)(bm + base)        = o0;
    *(ushort4*)(bm + base + 1024) = o1;
    *(ushort4*)(bm + base + 2048) = o2;
    *(ushort4*)(bm + base + 3072) = o3;
  }
}

// ---------------------------------------------------------------------------
// bf16 MFMA GEMM: Y = A[4096,1024] @ W[1024,1024]^T.
// Staging via global_load_lds (width 16), linear [128][32] LDS tiles.
// MODE 0: f32 flat; MODE 1: bf16 head-split; MODE 2: bf16 head-split transposed.
// ---------------------------------------------------------------------------
template <int MODE>
__global__ __launch_bounds__(256) void k_gemm(const ushort* __restrict__ A,
                                              const ushort* __restrict__ W,
                                              void* __restrict__ Yv,
                                              float scale) {
  __shared__ ushort At[128][32];   // linear: required by global_load_lds
  __shared__ ushort Wt[128][32];
  const int tid = threadIdx.x;
  const int l = tid & 63, w = tid >> 6;
  const int wm = (w >> 1) * 64, wn = (w & 1) * 64;
  const int r16 = l & 15, g = l >> 4;
  const int i0 = blockIdx.x * 128, j0 = blockIdx.y * 128;
  const int srow = (l >> 2), scol = (l & 3) << 3;
  f32x4 acc[4][4] = {};

  for (int k0 = 0; k0 < D_; k0 += 32) {
    __syncthreads();
#pragma unroll
    for (int u = 0; u < 2; ++u) {
      const int row = w * 32 + u * 16 + srow;
      gl_lds16(&A[(size_t)(i0 + row) * D_ + k0 + scol], &At[w * 32 + u * 16][0]);
      gl_lds16(&W[(size_t)(j0 + row) * D_ + k0 + scol], &Wt[w * 32 + u * 16][0]);
    }
    __syncthreads();
    short8 a0[4], b0[4];
#pragma unroll
    for (int i = 0; i < 4; ++i) a0[i] = *(const short8*)&At[wm + 16 * i + r16][g * 8];
#pragma unroll
    for (int j = 0; j < 4; ++j) b0[j] = *(const short8*)&Wt[wn + 16 * j + r16][g * 8];
#pragma unroll
    for (int i = 0; i < 4; ++i)
#pragma unroll
      for (int j = 0; j < 4; ++j)
        acc[i][j] = MFMA_BF16(a0[i], b0[j], acc[i][j], 0, 0, 0);
  }

#pragma unroll
  for (int i = 0; i < 4; ++i)
#pragma unroll
    for (int j = 0; j < 4; ++j) {
      if (MODE == 2) {
        const int row0 = i0 + wm + 16 * i + 4 * g;
        const int col = j0 + wn + 16 * j + r16;
        const int bb = row0 >> 10, s = row0 & 1023;
        const int hh = col >> 6, dh = col & 63;
        ushort4 pw;
        pw.x = f2bf(acc[i][j][0] * scale); pw.y = f2bf(acc[i][j][1] * scale);
        pw.z = f2bf(acc[i][j][2] * scale); pw.w = f2bf(acc[i][j][3] * scale);
        *(ushort4*)&((ushort*)Yv)[((size_t)(bb * H_ + hh) * DH_ + dh) * 1024 + s] = pw;
      } else {
#pragma unroll
        for (int r = 0; r < 4; ++r) {
          const int row = i0 + wm + 16 * i + 4 * g + r;
          const int col = j0 + wn + 16 * j + r16;
          const float vv = acc[i][j][r] * scale;
          if (MODE == 0) {
            ((float*)Yv)[(size_t)row * D_ + col] = vv;
          } else {
            const int b = row >> 10, t = row & 1023;
            const int h = col >> 6, dh = col & 63;
            ((ushort*)Yv)[(((size_t)(b * H_ + h) * 1024) + t) * DH_ + dh] = f2bf(vv);
          }
        }
      }
    }
}

// ---------------------------------------------------------------------------
// Column sum-of-exp2 via MFMA (unchanged).
// ---------------------------------------------------------------------------
__global__ __launch_bounds__(256, 4) void k_colstats(const ushort* __restrict__ Qh,
                                                     const ushort* __restrict__ Kh,
                                                     const ushort* __restrict__ biasm,
                                                     float* __restrict__ pc) {
  __shared__ ushort Qt[128][72];
  __shared__ ushort U[9216];
  ushort (*Kt)[72] = (ushort(*)[72])U;
  typedef ushort Row144[144];
  Row144* Bm0 = (Row144*)U;
  Row144* Bm1 = (Row144*)(U + 4608);

  const int bid = blockIdx.x;
  const int x8 = bid & 7;
  const int b = (bid >> 3) & 3;
  const int v = (bid >> 5) * 8 + x8;       // [0,1024): (h, st, tt)
  const int h = v >> 6, st = (v >> 3) & 7, tt = v & 7;
  const int s0 = st * 128, t0 = tt * 128;
  const int tid = threadIdx.x, l = tid & 63, w = tid >> 6;
  const int r16 = l & 15, g = l >> 4;

  const ushort* qsrc = Qh + ((size_t)((b * H_ + h) * 1024) + t0) * DH_;
  const ushort* ksrc = Kh + ((size_t)((b * H_ + h) * 1024) + s0) * DH_;
#pragma unroll
  for (int u = 0; u < 4; ++u) {
    const int lin = u * 256 + tid;
    const int row = lin >> 3, c8 = (lin & 7) << 3;
    *(uint4*)&Qt[row][c8] = *(const uint4*)&qsrc[(size_t)row * DH_ + c8];
    *(uint4*)&Kt[row][c8] = *(const uint4*)&ksrc[(size_t)row * DH_ + c8];
  }
  __syncthreads();

  f32x4 acc[8][2] = {};
  __builtin_amdgcn_s_setprio(1);
#pragma unroll
  for (int kc = 0; kc < 2; ++kc) {
    short8 bk0 = *(const short8*)&Kt[w * 32 + r16][kc * 32 + g * 8];
    short8 bk1 = *(const short8*)&Kt[w * 32 + 16 + r16][kc * 32 + g * 8];
#pragma unroll
    for (int i = 0; i < 8; ++i) {
      short8 a = *(const short8*)&Qt[16 * i + r16][kc * 32 + g * 8];
      acc[i][0] = MFMA_BF16(a, bk0, acc[i][0], 0, 0, 0);
      acc[i][1] = MFMA_BF16(a, bk1, acc[i][1], 0, 0, 0);
    }
  }
  __builtin_amdgcn_s_setprio(0);
  __syncthreads();

  const ushort* bsrc = biasm + ((size_t)h * 1024 + t0) * 1024 + s0;
#pragma unroll
  for (int u = 0; u < 2; ++u) {
    const int lin = u * 256 + tid;
    const int row = lin >> 4, c8 = (lin & 15) << 3;
    *(uint4*)&Bm0[row][c8] = *(const uint4*)&bsrc[(size_t)row * 1024 + c8];
  }
  __syncthreads();

  float cs0 = 0.f, cs1 = 0.f;
  const int col0 = w * 32 + r16;
#pragma unroll
  for (int c = 0; c < 4; ++c) {
    Row144* cur = (c & 1) ? Bm1 : Bm0;
    if (c < 3) {
      Row144* nxt = (c & 1) ? Bm0 : Bm1;
#pragma unroll
      for (int u = 0; u < 2; ++u) {
        const int lin = u * 256 + tid;
        const int row = lin >> 4, c8 = (lin & 15) << 3;
        *(uint4*)&nxt[row][c8] =
            *(const uint4*)&bsrc[(size_t)((c + 1) * 32 + row) * 1024 + c8];
      }
    }
#pragma unroll
    for (int ii = 0; ii < 2; ++ii) {
      const int i = 2 * c + ii;
      const int lrow = 16 * ii + 4 * g;
#pragma unroll
      for (int r = 0; r < 4; ++r) {
        cs0 += exp2_fast(acc[i][0][r] + bf2f(cur[lrow + r][col0]));
        cs1 += exp2_fast(acc[i][1][r] + bf2f(cur[lrow + r][col0 + 16]));
      }
    }
    __syncthreads();
  }

  cs0 += __shfl_xor(cs0, 16); cs0 += __shfl_xor(cs0, 32);
  cs1 += __shfl_xor(cs1, 16); cs1 += __shfl_xor(cs1, 32);
  if (g == 0) {
    const size_t base = ((size_t)b * 1024 + s0 + col0) * 128 + h * 8 + tt;
    pc[base] = cs0;
    pc[base + 16 * 128] = cs1;
  }
}

// ---------------------------------------------------------------------------
// Combine 128 partial sums per (b,s) -> Civ = 1/C.
// ---------------------------------------------------------------------------
__global__ __launch_bounds__(128) void k_combine(const float* __restrict__ pc,
                                                 float* __restrict__ Civ) {
  const int bs = blockIdx.x, tid = threadIdx.x;
  float c = pc[(size_t)bs * 128 + tid];
  __shared__ float sc[128];
  sc[tid] = c;
  __syncthreads();
  for (int off = 64; off > 0; off >>= 1) {
    if (tid < off) sc[tid] += sc[tid + off];
    __syncthreads();
  }
  if (tid == 0) {
    const float C = sc[0];
    Civ[bs] = (C > 0.f) ? 1.f / C : 0.f;
  }
}

// ---------------------------------------------------------------------------
// Attention pass (R14 structure, unchanged): 128-row t-tile, grid 512 =
// 2 blocks/CU fully resident, swapped QK, exp2+cvt_pk, XCD-local decode.
// ---------------------------------------------------------------------------
__global__ __launch_bounds__(256, 2) void k_attn(const ushort* __restrict__ Qh,
                                                 const ushort* __restrict__ Kh,
                                                 const ushort* __restrict__ VhT,
                                                 const ushort* __restrict__ biasm,
                                                 const float* __restrict__ Civ,
                                                 ushort* __restrict__ O) {
  __shared__ ushort Kt[128][68];     // 17408 B  (s rows of K chunk)
  __shared__ ushort VtT[64][132];    // 16896 B  (d rows, s cols)
  __shared__ ushort BmPt[128][132];  // 33792 B  (t rows, s cols; bias then P)
  __shared__ float Cih[128];
  __shared__ float Rp[4][128];

  const int bid = blockIdx.x;
  const int tt = bid >> 6;           // t-tile (8 of 128 rows)
  const int bh = bid & 63;           // XCD = bh % 8 for all tt
  const int b = bh >> 4, h = bh & 15;
  const int t0 = tt * 128;

  const int tid = threadIdx.x, l = tid & 63, w = tid >> 6;
  const int r16 = l & 15, g = l >> 4;
  const size_t kvbase = (size_t)bh * 1024 * DH_;
  const size_t vbase  = (size_t)bh * DH_ * 1024;

  short8 aq[8][2];
#pragma unroll
  for (int i = 0; i < 8; ++i) {
    const ushort* qr = Qh + ((size_t)bh * 1024 + t0 + 16 * i + r16) * DH_;
    aq[i][0] = *(const short8*)(qr + g * 8);
    aq[i][1] = *(const short8*)(qr + 32 + g * 8);
  }

  f32x4 aco[2][4] = {};
  float rloc[8] = {};

#pragma unroll 1
  for (int sc = 0; sc < 8; ++sc) {
    const int s0c = sc * 128;
    __syncthreads();

    {
      const ushort* ksrc = Kh + kvbase + (size_t)s0c * DH_;
#pragma unroll
      for (int u = 0; u < 4; ++u) {
        const int lin = u * 256 + tid;
        const int row = lin >> 3, c8 = (lin & 7) << 3;
        *(uint4*)&Kt[row][c8] = *(const uint4*)&ksrc[(size_t)row * DH_ + c8];
      }
      const ushort* vsrc = VhT + vbase + s0c;
#pragma unroll
      for (int u = 0; u < 4; ++u) {
        const int lin = u * 256 + tid;
        const int row = lin >> 4, c8 = (lin & 15) << 3;
        *(uint4*)&VtT[row][c8] = *(const uint4*)&vsrc[(size_t)row * 1024 + c8];
      }
      const ushort* bsrc = biasm + ((size_t)h * 1024 + t0) * 1024 + s0c;
#pragma unroll
      for (int u = 0; u < 8; ++u) {
        const int lin = u * 256 + tid;
        const int row = lin >> 4, c8 = (lin & 15) << 3;
        *(uint4*)&BmPt[row][c8] = *(const uint4*)&bsrc[(size_t)row * 1024 + c8];
      }
      if (tid < 128) Cih[tid] = Civ[(size_t)b * 1024 + s0c + tid];
    }
    __syncthreads();

    // ---- QK (A = K from LDS, B = Q regs) + exp, per jf ----
#pragma unroll
    for (int j2 = 0; j2 < 2; ++j2) {
      const int jf = 2 * w + j2;
      f32x4 as[8] = {};
      short8 kf0 = *(const short8*)&Kt[16 * jf + r16][g * 8];
      short8 kf1 = *(const short8*)&Kt[16 * jf + r16][32 + g * 8];
      __builtin_amdgcn_s_setprio(1);
#pragma unroll
      for (int i = 0; i < 8; ++i) {
        as[i] = MFMA_BF16(kf0, aq[i][0], as[i], 0, 0, 0);
        as[i] = MFMA_BF16(kf1, aq[i][1], as[i], 0, 0, 0);
      }
      __builtin_amdgcn_s_setprio(0);
      const int scol = 16 * jf + 4 * g;
      const float4 cv = *(const float4*)&Cih[scol];
#pragma unroll
      for (int i = 0; i < 8; ++i) {
        const int srow = 16 * i + r16;
        ushort4 bv4 = *(const ushort4*)&BmPt[srow][scol];
        const float p0 = exp2_fast(as[i][0] + bf2f(bv4.x)) * cv.x;
        const float p1 = exp2_fast(as[i][1] + bf2f(bv4.y)) * cv.y;
        const float p2 = exp2_fast(as[i][2] + bf2f(bv4.z)) * cv.z;
        const float p3 = exp2_fast(as[i][3] + bf2f(bv4.w)) * cv.w;
        rloc[i] += (p0 + p1) + (p2 + p3);
        uint2 pw;
        pw.x = cvt_pk_bf16(p0, p1);
        pw.y = cvt_pk_bf16(p2, p3);
        *(uint2*)&BmPt[srow][scol] = pw;
      }
    }
    __syncthreads();

    // ---- PV: wave w owns t rows 32w..32w+31 (rg = 0,1) ----
    __builtin_amdgcn_s_setprio(1);
#pragma unroll
    for (int rg = 0; rg < 2; ++rg) {
#pragma unroll
      for (int kc = 0; kc < 4; ++kc) {
        short8 ap = *(const short8*)&BmPt[32 * w + 16 * rg + r16][kc * 32 + g * 8];
#pragma unroll
        for (int j = 0; j < 4; ++j) {
          short8 bv = *(const short8*)&VtT[16 * j + r16][kc * 32 + g * 8];
          aco[rg][j] = MFMA_BF16(ap, bv, aco[rg][j], 0, 0, 0);
        }
      }
    }
    __builtin_amdgcn_s_setprio(0);
  }

  // row sums: reduce over g-lanes (xor 16, 32), then across waves via Rp
#pragma unroll
  for (int i = 0; i < 8; ++i) {
    float vsum = rloc[i];
    vsum += __shfl_xor(vsum, 16);
    vsum += __shfl_xor(vsum, 32);
    if (l < 16) Rp[w][16 * i + r16] = vsum;
  }
  __syncthreads();

#pragma unroll
  for (int rg = 0; rg < 2; ++rg)
#pragma unroll
    for (int j = 0; j < 4; ++j)
#pragma unroll
      for (int r = 0; r < 4; ++r) {
        const int tl = 32 * w + 16 * rg + 4 * g + r;
        const float R = Rp[0][tl] + Rp[1][tl] + Rp[2][tl] + Rp[3][tl];
        const float o = aco[rg][j][r] / (R + EPSV);
        const int d = 16 * j + r16;
        O[((size_t)(b * 1024) + t0 + tl) * D_ + h * DH_ + d] = f2bf(o);
      }
}

// ---------------------------------------------------------------------------
extern "C" void kernel_launch(void* const* d_in, const int* in_sizes, int n_in,
                              void* d_out, int out_size, void* d_ws, size_t ws_size,
                              hipStream_t stream) {
  (void)in_sizes; (void)n_in; (void)out_size; (void)ws_size;
  const float* q    = (const float*)d_in[0];
  const float* k    = (const float*)d_in[1];
  const float* v    = (const float*)d_in[2];
  const int*   mask = (const int*)d_in[3];
  const float* bias = (const float*)d_in[4];
  const float* Wq   = (const float*)d_in[5];
  const float* Wk   = (const float*)d_in[6];
  const float* Wv   = (const float*)d_in[7];
  const float* Wo   = (const float*)d_in[8];
  float* out = (float*)d_out;

  ushort* qb   = (ushort*)d_ws;
  ushort* kb   = qb + 4194304;
  ushort* vb   = kb + 4194304;
  ushort* Wqb  = vb + 4194304;
  ushort* Wkb  = Wqb + 1048576;
  ushort* Wvb  = Wkb + 1048576;
  ushort* Wob  = Wvb + 1048576;
  ushort* Qh   = Wob + 1048576;
  ushort* Kh   = Qh + 4194304;
  ushort* VhT  = Kh + 4194304;
  ushort* Ob   = VhT + 4194304;
  ushort* bm   = Ob + 4194304;
  float*  pc   = (float*)(bm + 16777216);
  float*  Civ  = pc + 524288;

  k_prep<<<8192, 256, 0, stream>>>(q, k, v, Wq, Wk, Wv, Wo, bias, mask,
                                   qb, kb, vb, Wqb, Wkb, Wvb, Wob, bm);

  k_gemm<1><<<dim3(32, 8), 256, 0, stream>>>(qb, Wqb, Qh, SCALE_Q);
  k_gemm<1><<<dim3(32, 8), 256, 0, stream>>>(kb, Wkb, Kh, 1.0f);
  k_gemm<2><<<dim3(32, 8), 256, 0, stream>>>(vb, Wvb, VhT, 1.0f);

  k_colstats<<<4096, 256, 0, stream>>>(Qh, Kh, bm, pc);
  k_combine<<<4096, 128, 0, stream>>>(pc, Civ);
  k_attn<<<512, 256, 0, stream>>>(Qh, Kh, VhT, bm, Civ, Ob);

  k_gemm<0><<<dim3(32, 8), 256, 0, stream>>>(Ob, Wob, out, 1.0f);
}